// Round 12
// baseline (121.163 us; speedup 1.0000x reference)
//
#include <hip/hip_runtime.h>

// FETANetwork fused: B=1024, N=64, F=128, H=8. One block per batch.
// out[b,i] = (sum_{j!=i} f_ij.wl + sum_{j!=i} f_ji.wr)/63 + bsf + zeroth[b,i]
// f_ij = selu(selu(hi_i + hj_j) @ Wf1 + bf1),  hi = x@Wa + bf0, hj = x@Wb
// SELU outer scale folded into Wf1 and wsf.
// NOTE: selu MUST use the explicit select. The min-trick
// min(x, alpha*(e^x-1)) is WRONG for x < ~-1.85 (g(x) > x there).

#define SELU_ALPHA 1.6732632423543772f
#define SELU_SCALE 1.0507009873554805f

__device__ __forceinline__ float selu_full(float x) {
    float neg = fmaf(SELU_ALPHA, __expf(x), -SELU_ALPHA);
    return SELU_SCALE * (x > 0.0f ? x : neg);
}
__device__ __forceinline__ float sel_unscaled(float x) {   // selu(x) / SELU_SCALE
    float neg = fmaf(SELU_ALPHA, __expf(x), -SELU_ALPHA);
    return x > 0.0f ? x : neg;
}

__global__ __launch_bounds__(256) void feta_fused(
    const float* __restrict__ x,
    const float* __restrict__ Wz0, const float* __restrict__ bz0,
    const float* __restrict__ Wz1, const float* __restrict__ bz1,
    const float* __restrict__ wsz, const float* __restrict__ bsz,
    const float* __restrict__ Wf0, const float* __restrict__ bf0,
    const float* __restrict__ Wf1, const float* __restrict__ bf1,
    const float* __restrict__ wsf, const float* __restrict__ bsf,
    float* __restrict__ out)
{
    // smem: phase1 = xs[64][129] (33 KB); phase2 reuse = ts[64][65]+cup[256]+rsp[256]
    __shared__ float smem[64 * 129];
    __shared__ float his[64 * 8];    // row-major stride 8: 32B-aligned b128 broadcasts
    __shared__ float hjs[8 * 64];    // column-major: conflict-free lane-distinct b32
    __shared__ float zs[64];

    const int b = blockIdx.x;
    const int t = threadIdx.x;
    const int w = t >> 6;
    const int l = t & 63;

    // ---- stage x tile (64 x 128), row-major stride 129 (odd -> conflict-free
    //      column reads); coalesced global float4
    {
        const float4* xin = (const float4*)(x + (long long)b * 8192);
        #pragma unroll
        for (int i = 0; i < 8; ++i) {
            int f4 = i * 256 + t;            // 0..2047
            float4 v = xin[f4];
            int r  = f4 >> 5;
            int kq = f4 & 31;
            *(float4*)&smem[r * 129 + kq * 4] = v;
        }
    }
    __syncthreads();

    // ---- phase 1: per-wave roles. Lane = row. Weight loads are wave-uniform
    //      (const __restrict__ + uniform index -> s_load); x from LDS b32,
    //      stride 129 -> 2 lanes/bank = free.
    const float* xr = &smem[l * 129];
    if (w == 0) {
        // az = x@Wz0 + bz0, then full zeroth path in-register
        float acc[8];
        #pragma unroll
        for (int c = 0; c < 8; ++c) acc[c] = bz0[c];
        #pragma unroll 8
        for (int k = 0; k < 128; ++k) {
            float xk = xr[k];
            #pragma unroll
            for (int c = 0; c < 8; ++c) acc[c] = fmaf(xk, Wz0[k * 8 + c], acc[c]);
        }
        float h0[8];
        #pragma unroll
        for (int c = 0; c < 8; ++c) h0[c] = selu_full(acc[c]);
        float zacc = bsz[0];
        #pragma unroll
        for (int c = 0; c < 8; ++c) {
            float s = bz1[c];
            #pragma unroll
            for (int r = 0; r < 8; ++r) s = fmaf(h0[r], Wz1[r * 8 + c], s);
            zacc = fmaf(selu_full(s), wsz[c], zacc);
        }
        zs[l] = selu_full(zacc);
    } else if (w == 1) {
        // hi = x@Wa + bf0
        float acc[8];
        #pragma unroll
        for (int c = 0; c < 8; ++c) acc[c] = bf0[c];
        #pragma unroll 8
        for (int k = 0; k < 128; ++k) {
            float xk = xr[k];
            #pragma unroll
            for (int c = 0; c < 8; ++c) acc[c] = fmaf(xk, Wf0[k * 8 + c], acc[c]);
        }
        #pragma unroll
        for (int c = 0; c < 8; ++c) his[l * 8 + c] = acc[c];
    } else {
        // hj = x@Wb, split: wave2 -> cols 0..3, wave3 -> cols 4..7
        const int c0 = (w == 3) ? 4 : 0;
        const float* wb = Wf0 + 1024 + c0;
        float acc[4];
        #pragma unroll
        for (int c = 0; c < 4; ++c) acc[c] = 0.f;
        #pragma unroll 8
        for (int k = 0; k < 128; ++k) {
            float xk = xr[k];
            #pragma unroll
            for (int c = 0; c < 4; ++c) acc[c] = fmaf(xk, wb[k * 8 + c], acc[c]);
        }
        #pragma unroll
        for (int c = 0; c < 4; ++c) hjs[(c0 + c) * 64 + l] = acc[c];
    }

    // phase-2 weights (uniform -> s_load; SELU scale folded into W/wl/wr)
    float W[64], bfv[8], wl[8], wr[8];
    #pragma unroll
    for (int i = 0; i < 64; ++i) W[i] = SELU_SCALE * Wf1[i];
    #pragma unroll
    for (int c = 0; c < 8; ++c) {
        bfv[c] = bf1[c];
        wl[c]  = SELU_SCALE * wsf[c];
        wr[c]  = SELU_SCALE * wsf[8 + c];
    }
    const float bsfv = bsf[0];
    __syncthreads();

    // ---- phase 2: thread (w,l): j = l, i = w*16+k for k=0..15
    float hjr[8];
    #pragma unroll
    for (int c = 0; c < 8; ++c) hjr[c] = hjs[c * 64 + l];   // conflict-free b32

    float* ts  = smem;             // [64][65] in dead xs space
    float* cup = smem + 64 * 65;   // [4][64]
    float* rsp = cup + 256;        // [4][64]

    float cu_acc = 0.f;
    #pragma unroll 4
    for (int k = 0; k < 16; ++k) {
        const int i = w * 16 + k;               // wave-uniform
        const float* hrow = &his[i * 8];        // 32B-aligned LDS broadcast
        float g[8];
        #pragma unroll
        for (int c = 0; c < 8; ++c) g[c] = sel_unscaled(hrow[c] + hjr[c]);
        float tt = 0.f, uu = 0.f;
        #pragma unroll
        for (int c = 0; c < 8; ++c) {
            float s = bfv[c];
            #pragma unroll
            for (int r = 0; r < 8; ++r) s = fmaf(g[r], W[r * 8 + c], s);
            float fv = sel_unscaled(s);
            tt = fmaf(fv, wl[c], tt);
            uu = fmaf(fv, wr[c], uu);
        }
        if (i == l) { tt = 0.f; uu = 0.f; }     // diagonal mask
        cu_acc += uu;
        ts[i * 65 + l] = tt;                    // stride-1 across lanes: free
    }
    cup[w * 64 + l] = cu_acc;
    __syncthreads();

    // row partials: thread (w,l) sums row l over j in [w*16, w*16+16)
    float rp = 0.f;
    #pragma unroll
    for (int m = 0; m < 16; ++m) rp += ts[l * 65 + w * 16 + m];
    rsp[w * 64 + l] = rp;
    __syncthreads();

    if (t < 64) {
        float rsum = rsp[t] + rsp[64 + t] + rsp[128 + t] + rsp[192 + t];
        float csum = cup[t] + cup[64 + t] + cup[128 + t] + cup[192 + t];
        out[(long long)b * 64 + t] =
            (rsum + csum) * (1.0f / 63.0f) + bsfv + zs[t];
    }
}

extern "C" void kernel_launch(void* const* d_in, const int* in_sizes, int n_in,
                              void* d_out, int out_size, void* d_ws, size_t ws_size,
                              hipStream_t stream) {
    const float* x   = (const float*)d_in[0];
    const float* Wz0 = (const float*)d_in[1];
    const float* bz0 = (const float*)d_in[2];
    const float* Wz1 = (const float*)d_in[3];
    const float* bz1 = (const float*)d_in[4];
    const float* wsz = (const float*)d_in[5];
    const float* bsz = (const float*)d_in[6];
    const float* Wf0 = (const float*)d_in[7];
    const float* bf0 = (const float*)d_in[8];
    const float* Wf1 = (const float*)d_in[9];
    const float* bf1 = (const float*)d_in[10];
    const float* wsf = (const float*)d_in[11];
    const float* bsf = (const float*)d_in[12];
    float* out = (float*)d_out;

    feta_fused<<<1024, 256, 0, stream>>>(x, Wz0, bz0, Wz1, bz1, wsz, bsz,
                                         Wf0, bf0, Wf1, bf1, wsf, bsf, out);
}